// Round 2
// baseline (364.363 us; speedup 1.0000x reference)
//
#include <hip/hip_runtime.h>
#include <hip/hip_bf16.h>
#include <math.h>

// ---------------------------------------------------------------------------
// DisplacementTensors: rad = MLP(radial_encode(|r|)) depends on |r| only ->
// tabulate F(d), F(d)@w_v, F(d)@w_d on a grid, linear-interp per edge.
// Segment-sum via CSR (hist/scan/scatter), one wave per node, outputs written
// directly from registers.  Input/output dtype (bf16 vs f32) detected at
// runtime on-device (flag in d_ws) since the harness flavor is ambiguous.
// ---------------------------------------------------------------------------

#define TSIZE 2048          // table entries
#define DMAX  2.0f          // RBF centers <=1, width 0.125 -> F const beyond ~2
#define NPB   4             // waves (nodes) per block in k_nodes

__device__ __forceinline__ float b2f(__hip_bfloat16 x) { return __bfloat162float(x); }
__device__ __forceinline__ float lrelu(float x) { return x > 0.0f ? x : 0.1f * x; }

__device__ __forceinline__ float ldf(const void* p, int i, bool f32) {
    return f32 ? ((const float*)p)[i]
               : __bfloat162float(((const __hip_bfloat16*)p)[i]);
}
__device__ __forceinline__ void stf(void* p, size_t i, float v, bool f32) {
    if (f32) ((float*)p)[i] = v;
    else     ((__hip_bfloat16*)p)[i] = __float2bfloat16(v);
}

// --- dtype detection: flag=1 if buffers are float32, 0 if bf16 -------------
// Reading float32 data as bf16 half-words yields non-finite / huge values for
// ~40% of low halves; genuine bf16 N(0,1) data never exceeds 1e5.
__global__ void k_detect(const void* r, int nbf16, int* flag) {
    __shared__ int bad;
    if (threadIdx.x == 0) bad = 0;
    __syncthreads();
    const __hip_bfloat16* p = (const __hip_bfloat16*)r;
    int local = 0;
    for (int i = threadIdx.x; i < nbf16; i += blockDim.x) {
        float v = __bfloat162float(p[i]);
        if (!isfinite(v) || fabsf(v) > 1e5f) local = 1;
    }
    if (local) atomicOr(&bad, 1);
    __syncthreads();
    if (threadIdx.x == 0) flag[0] = bad;
}

// --- build the three LUTs: one block (64 threads) per table entry ----------
__global__ void k_table(const void* __restrict__ w_rad,
                        const void* __restrict__ b_rad,
                        const void* __restrict__ w_direct,
                        const void* __restrict__ w1,
                        const void* __restrict__ b1,
                        const void* __restrict__ w2,
                        const void* __restrict__ b2,
                        const void* __restrict__ w3,
                        const void* __restrict__ b3,
                        const void* __restrict__ w_v,
                        const void* __restrict__ w_d,
                        const int* __restrict__ flag,
                        float* __restrict__ tab_a,
                        float* __restrict__ tab_v,
                        float* __restrict__ tab_d) {
    __shared__ float Lh[32];
    __shared__ float Lt1[64];
    __shared__ float Lt2[64];
    __shared__ float Lrad[32];

    const bool f32 = flag[0] != 0;
    const int e = blockIdx.x;
    const int j = threadIdx.x;
    const float d = (float)e * (DMAX / (float)(TSIZE - 1));

    // 8 Gaussian RBFs, centers linspace(0,1,8), width 1/8
    float enc[8];
#pragma unroll
    for (int k = 0; k < 8; k++) {
        float c = (float)k * (1.0f / 7.0f);
        float t = (d - c) * 8.0f;
        enc[k] = expf(-t * t);
    }

    if (j < 32) {
        float s = ldf(b_rad, j, f32);
#pragma unroll
        for (int k = 0; k < 8; k++) s += enc[k] * ldf(w_rad, k * 32 + j, f32);
        Lh[j] = s;
    }
    __syncthreads();

    {   // t1 = lrelu(h @ w1 + b1)  [64]
        float s = ldf(b1, j, f32);
        for (int i = 0; i < 32; i++) s += Lh[i] * ldf(w1, i * 64 + j, f32);
        Lt1[j] = lrelu(s);
    }
    __syncthreads();

    {   // t2 = lrelu(t1 @ w2 + b2) [64]
        float s = ldf(b2, j, f32);
        for (int i = 0; i < 64; i++) s += Lt1[i] * ldf(w2, i * 64 + j, f32);
        Lt2[j] = lrelu(s);
    }
    __syncthreads();

    if (j < 32) {   // rad = h @ w_direct + (t2 @ w3 + b3)
        float s = ldf(b3, j, f32);
        for (int i = 0; i < 64; i++) s += Lt2[i] * ldf(w3, i * 32 + j, f32);
        for (int i = 0; i < 32; i++) s += Lh[i] * ldf(w_direct, i * 32 + j, f32);
        Lrad[j] = s;
        tab_a[e * 32 + j] = s;
    }
    __syncthreads();

    if (j < 32) {   // tab_v = rad @ w_v, tab_d = rad @ w_d
        float sv = 0.0f, sd = 0.0f;
        for (int i = 0; i < 32; i++) {
            float ri = Lrad[i];
            sv += ri * ldf(w_v, i * 32 + j, f32);
            sd += ri * ldf(w_d, i * 32 + j, f32);
        }
        tab_v[e * 32 + j] = sv;
        tab_d[e * 32 + j] = sd;
    }
}

// --- per-edge precompute: (rs0, rs1, rs2, u) -------------------------------
__global__ void k_pre(const void* __restrict__ r_ij, const int* __restrict__ flag,
                      float4* __restrict__ ep, int E) {
    int e = blockIdx.x * blockDim.x + threadIdx.x;
    if (e >= E) return;
    const bool f32 = flag[0] != 0;
    const float x = ldf(r_ij, 3 * e + 0, f32);
    const float y = ldf(r_ij, 3 * e + 1, f32);
    const float z = ldf(r_ij, 3 * e + 2, f32);
    const float d2 = x * x + y * y + z * z;
    const float dd = sqrtf(d2);
    const float inv = rsqrtf(1.0f + 49.0f * d2);       // tens_sigmoid(7*r)
    const float u = fminf(dd, DMAX) * ((float)(TSIZE - 1) / DMAX);
    ep[e] = make_float4(7.0f * x * inv, 7.0f * y * inv, 7.0f * z * inv, u);
}

// --- CSR construction ------------------------------------------------------
__global__ void k_zero(int* __restrict__ p, int n) {
    int i = blockIdx.x * blockDim.x + threadIdx.x;
    if (i < n) p[i] = 0;
}

__global__ void k_hist(const int* __restrict__ src, int* __restrict__ counts, int E) {
    int e = blockIdx.x * blockDim.x + threadIdx.x;
    if (e < E) atomicAdd(&counts[src[e]], 1);
}

__global__ void k_scan(const int* __restrict__ counts, int* __restrict__ rowstart,
                       int* __restrict__ cursor, int N, int E) {
    __shared__ int part[1024];
    const int t = threadIdx.x;
    const int CH = (N + 1023) / 1024;
    const int lo = t * CH;
    const int hi = min(lo + CH, N);

    int s = 0;
    for (int i = lo; i < hi; i++) s += counts[i];
    part[t] = s;
    __syncthreads();

    for (int off = 1; off < 1024; off <<= 1) {
        int v = part[t];
        int w = (t >= off) ? part[t - off] : 0;
        __syncthreads();
        part[t] = v + w;
        __syncthreads();
    }

    int run = (t == 0) ? 0 : part[t - 1];
    for (int i = lo; i < hi; i++) {
        rowstart[i] = run;
        cursor[i]   = run;
        run += counts[i];
    }
    if (t == 0) rowstart[N] = E;
}

__global__ void k_scatter(const int* __restrict__ src, int* __restrict__ cursor,
                          int* __restrict__ perm, int E) {
    int e = blockIdx.x * blockDim.x + threadIdx.x;
    if (e < E) {
        int pos = atomicAdd(&cursor[src[e]], 1);
        perm[pos] = e;
    }
}

// --- per-node accumulation: one wave per node ------------------------------
// lane = (a = lane&31) x (half = lane>>5). half0: {A_a, v*, d0*}; half1: {d1*, d2*}.
__global__ void __launch_bounds__(64 * NPB) k_nodes(
    const float4* __restrict__ ep,          // may be null -> compute inline
    const void* __restrict__ r_ij,
    const int* __restrict__ rowstart,
    const int* __restrict__ perm,
    const float* __restrict__ tab_a,
    const float* __restrict__ tab_v,
    const float* __restrict__ tab_d,
    const int* __restrict__ flag,
    void* __restrict__ out, int N) {
    const int wave = threadIdx.x >> 6;
    const int lane = threadIdx.x & 63;
    const int n = blockIdx.x * NPB + wave;
    if (n >= N) return;
    const int a = lane & 31;
    const int half = lane >> 5;
    const bool f32 = flag[0] != 0;

    const int s0 = rowstart[n];
    const int s1 = rowstart[n + 1];

    float acc0 = 0.f, acc1 = 0.f, acc2 = 0.f, acc3 = 0.f, acc4 = 0.f, acc5 = 0.f, acc6 = 0.f;

    for (int idx = s0; idx < s1; idx++) {
        const int e = perm[idx];
        float rs0, rs1, rs2, u;
        if (ep) {
            float4 q = ep[e];
            rs0 = q.x; rs1 = q.y; rs2 = q.z; u = q.w;
        } else {
            const float x = ldf(r_ij, 3 * e + 0, f32);
            const float y = ldf(r_ij, 3 * e + 1, f32);
            const float z = ldf(r_ij, 3 * e + 2, f32);
            const float d2 = x * x + y * y + z * z;
            const float inv = rsqrtf(1.0f + 49.0f * d2);
            rs0 = 7.0f * x * inv; rs1 = 7.0f * y * inv; rs2 = 7.0f * z * inv;
            u = fminf(sqrtf(d2), DMAX) * ((float)(TSIZE - 1) / DMAX);
        }
        int i0 = min((int)u, TSIZE - 2);
        const float f = u - (float)i0;
        const int b0 = i0 * 32 + a;

        float ra = tab_a[b0], ra1 = tab_a[b0 + 32];
        float rv = tab_v[b0], rv1 = tab_v[b0 + 32];
        float rd = tab_d[b0], rd1 = tab_d[b0 + 32];
        ra += f * (ra1 - ra);
        rv += f * (rv1 - rv);
        rd += f * (rd1 - rd);

        if (half == 0) {
            acc0 += ra;
            acc1 += rv * rs0; acc2 += rv * rs1; acc3 += rv * rs2;
            const float t = rd * rs0;
            acc4 += t * rs0; acc5 += t * rs1; acc6 += t * rs2;
        } else {
            const float t1 = rd * rs1, t2 = rd * rs2;
            acc0 += t1 * rs0; acc1 += t1 * rs1; acc2 += t1 * rs2;
            acc3 += t2 * rs0; acc4 += t2 * rs1; acc5 += t2 * rs2;
        }
    }

    const size_t baseV = (size_t)N * 32;
    const size_t baseD = (size_t)N * 128;
    if (half == 0) {
        stf(out, (size_t)n * 32 + a, acc0, f32);
        const size_t vb = baseV + (size_t)n * 96 + a * 3;
        stf(out, vb + 0, acc1, f32);
        stf(out, vb + 1, acc2, f32);
        stf(out, vb + 2, acc3, f32);
        const size_t db = baseD + (size_t)n * 288 + a * 9;
        stf(out, db + 0, acc4, f32);
        stf(out, db + 1, acc5, f32);
        stf(out, db + 2, acc6, f32);
    } else {
        const size_t db = baseD + (size_t)n * 288 + a * 9;
        stf(out, db + 3, acc0, f32);
        stf(out, db + 4, acc1, f32);
        stf(out, db + 5, acc2, f32);
        stf(out, db + 6, acc3, f32);
        stf(out, db + 7, acc4, f32);
        stf(out, db + 8, acc5, f32);
    }
}

extern "C" void kernel_launch(void* const* d_in, const int* in_sizes, int n_in,
                              void* d_out, int out_size, void* d_ws, size_t ws_size,
                              hipStream_t stream) {
    const void* r_ij     = d_in[0];
    const void* w_rad    = d_in[1];
    const void* b_rad    = d_in[2];
    const void* w_direct = d_in[3];
    const void* w1       = d_in[4];
    const void* b1       = d_in[5];
    const void* w2       = d_in[6];
    const void* b2       = d_in[7];
    const void* w3       = d_in[8];
    const void* b3       = d_in[9];
    const void* w_v      = d_in[10];
    const void* w_d      = d_in[11];
    const int* edges_src = (const int*)d_in[12];

    const int E = in_sizes[12];
    const int N = out_size / 416;   // 32 + 96 + 288 per node

    // workspace layout
    const size_t epBytes  = (size_t)E * 16;
    const size_t tabBytes = (size_t)3 * TSIZE * 32 * 4;
    const size_t intBytes = (size_t)(4 + 3 * N + 1 + E) * 4;
    const bool use_ep = ws_size >= epBytes + tabBytes + intBytes + 64;

    char* w = (char*)d_ws;
    float4* ep = use_ep ? (float4*)w : nullptr;
    float* tab_a = (float*)(w + (use_ep ? epBytes : 0));
    float* tab_v = tab_a + TSIZE * 32;
    float* tab_d = tab_v + TSIZE * 32;
    int* flag    = (int*)(tab_d + TSIZE * 32);
    int* counts  = flag + 4;
    int* rowstart = counts + N;       // N+1
    int* cursor  = rowstart + N + 1;
    int* perm    = cursor + N;        // E

    int nprobe = in_sizes[0] < 8192 ? in_sizes[0] : 8192;
    k_detect<<<1, 256, 0, stream>>>(r_ij, nprobe, flag);
    k_table<<<TSIZE, 64, 0, stream>>>(w_rad, b_rad, w_direct, w1, b1, w2, b2,
                                      w3, b3, w_v, w_d, flag, tab_a, tab_v, tab_d);
    if (use_ep)
        k_pre<<<(E + 255) / 256, 256, 0, stream>>>(r_ij, flag, ep, E);
    k_zero<<<(N + 255) / 256, 256, 0, stream>>>(counts, N);
    k_hist<<<(E + 255) / 256, 256, 0, stream>>>(edges_src, counts, E);
    k_scan<<<1, 1024, 0, stream>>>(counts, rowstart, cursor, N, E);
    k_scatter<<<(E + 255) / 256, 256, 0, stream>>>(edges_src, cursor, perm, E);
    k_nodes<<<(N + NPB - 1) / NPB, 64 * NPB, 0, stream>>>(
        ep, r_ij, rowstart, perm, tab_a, tab_v, tab_d, flag, d_out, N);
}

// Round 3
// 320.662 us; speedup vs baseline: 1.1363x; 1.1363x over previous
//
#include <hip/hip_runtime.h>
#include <hip/hip_bf16.h>
#include <math.h>

// ---------------------------------------------------------------------------
// DisplacementTensors: rad = MLP(radial_encode(|r|)) depends only on |r| ->
// tabulate F(d), F(d)@w_v, F(d)@w_d (TSIZE grid, linear interp).
// CSR segment-sum: rank (atomic) -> scan -> place edge payload (rs,u) directly
// into CSR order -> one wave per node streams its contiguous payload slice.
// Input/output dtype (bf16 vs f32) detected at runtime (flag in d_ws).
// ---------------------------------------------------------------------------

#define TSIZE 1024
#define DMAX  2.0f          // RBF centers <=1, width 1/8 -> F const beyond ~2
#define NPB   4             // waves (nodes) per block in k_nodes

__device__ __forceinline__ float lrelu(float x) { return x > 0.0f ? x : 0.1f * x; }

__device__ __forceinline__ float ldf(const void* p, int i, bool f32) {
    return f32 ? ((const float*)p)[i]
               : __bfloat162float(((const __hip_bfloat16*)p)[i]);
}
__device__ __forceinline__ void stf(void* p, size_t i, float v, bool f32) {
    if (f32) ((float*)p)[i] = v;
    else     ((__hip_bfloat16*)p)[i] = __float2bfloat16(v);
}

// --- dtype detection: flag=1 if buffers are float32, 0 if bf16 -------------
__global__ void k_detect(const void* r, int nbf16, int* flag) {
    __shared__ int bad;
    if (threadIdx.x == 0) bad = 0;
    __syncthreads();
    const __hip_bfloat16* p = (const __hip_bfloat16*)r;
    int local = 0;
    for (int i = threadIdx.x; i < nbf16; i += blockDim.x) {
        float v = __bfloat162float(p[i]);
        if (!isfinite(v) || fabsf(v) > 1e5f) local = 1;
    }
    if (local) atomicOr(&bad, 1);
    __syncthreads();
    if (threadIdx.x == 0) flag[0] = bad;
}

// --- LUT build: 128 blocks x 8 entries, weights staged in LDS --------------
// LDS float offsets
#define O_WRAD 0
#define O_BRAD 256
#define O_WDIR 288
#define O_W1   1312
#define O_B1   3360
#define O_W2   3424
#define O_B2   7520
#define O_W3   7584
#define O_B3   9632
#define O_WV   9664
#define O_WD   10688
#define W_TOT  11712

__device__ __forceinline__ void load_seg(float* dst, const void* src, int cnt,
                                         bool f32, int tid) {
    for (int i = tid; i < cnt; i += 64) dst[i] = ldf(src, i, f32);
}

__global__ void __launch_bounds__(64) k_table(
        const void* __restrict__ w_rad, const void* __restrict__ b_rad,
        const void* __restrict__ w_direct,
        const void* __restrict__ w1, const void* __restrict__ b1,
        const void* __restrict__ w2, const void* __restrict__ b2,
        const void* __restrict__ w3, const void* __restrict__ b3,
        const void* __restrict__ w_v, const void* __restrict__ w_d,
        const int* __restrict__ flag,
        float* __restrict__ tab_a, float* __restrict__ tab_v,
        float* __restrict__ tab_d) {
    __shared__ float W[W_TOT];
    __shared__ float Lh[32], Lt1[64], Lt2[64], Lrad[32];

    const bool f32 = flag[0] != 0;
    const int j = threadIdx.x;

    load_seg(W + O_WRAD, w_rad,    256,  f32, j);
    load_seg(W + O_BRAD, b_rad,    32,   f32, j);
    load_seg(W + O_WDIR, w_direct, 1024, f32, j);
    load_seg(W + O_W1,   w1,       2048, f32, j);
    load_seg(W + O_B1,   b1,       64,   f32, j);
    load_seg(W + O_W2,   w2,       4096, f32, j);
    load_seg(W + O_B2,   b2,       64,   f32, j);
    load_seg(W + O_W3,   w3,       2048, f32, j);
    load_seg(W + O_B3,   b3,       32,   f32, j);
    load_seg(W + O_WV,   w_v,      1024, f32, j);
    load_seg(W + O_WD,   w_d,      1024, f32, j);
    __syncthreads();

    const int per = TSIZE / 128;                 // 8 entries per block
    const int base = blockIdx.x * per;

    for (int e = base; e < base + per; e++) {
        const float d = (float)e * (DMAX / (float)(TSIZE - 1));
        float enc[8];
#pragma unroll
        for (int k = 0; k < 8; k++) {
            float t = (d - (float)k * (1.0f / 7.0f)) * 8.0f;
            enc[k] = expf(-t * t);
        }

        if (j < 32) {
            float s = W[O_BRAD + j];
#pragma unroll
            for (int k = 0; k < 8; k++) s += enc[k] * W[O_WRAD + k * 32 + j];
            Lh[j] = s;
        }
        __syncthreads();

        {   // t1 = lrelu(h @ w1 + b1) [64]
            float s = W[O_B1 + j];
            for (int i = 0; i < 32; i++) s += Lh[i] * W[O_W1 + i * 64 + j];
            Lt1[j] = lrelu(s);
        }
        __syncthreads();

        {   // t2 = lrelu(t1 @ w2 + b2) [64]
            float s = W[O_B2 + j];
            for (int i = 0; i < 64; i++) s += Lt1[i] * W[O_W2 + i * 64 + j];
            Lt2[j] = lrelu(s);
        }
        __syncthreads();

        if (j < 32) {   // rad = h @ w_direct + (t2 @ w3 + b3)
            float s = W[O_B3 + j];
            for (int i = 0; i < 64; i++) s += Lt2[i] * W[O_W3 + i * 32 + j];
            for (int i = 0; i < 32; i++) s += Lh[i] * W[O_WDIR + i * 32 + j];
            Lrad[j] = s;
            tab_a[e * 32 + j] = s;
        }
        __syncthreads();

        if (j < 32) {   // tab_v = rad @ w_v, tab_d = rad @ w_d
            float sv = 0.0f, sd = 0.0f;
            for (int i = 0; i < 32; i++) {
                float ri = Lrad[i];
                sv += ri * W[O_WV + i * 32 + j];
                sd += ri * W[O_WD + i * 32 + j];
            }
            tab_v[e * 32 + j] = sv;
            tab_d[e * 32 + j] = sd;
        }
        __syncthreads();
    }
}

// --- CSR construction ------------------------------------------------------
__global__ void k_zero(int* __restrict__ p, int n) {
    int i = blockIdx.x * blockDim.x + threadIdx.x;
    if (i < n) p[i] = 0;
}

// rank[e] = within-node arrival order
__global__ void k_rank(const int* __restrict__ src, int* __restrict__ counts,
                       int* __restrict__ rank, int E) {
    int e = blockIdx.x * blockDim.x + threadIdx.x;
    if (e < E) rank[e] = atomicAdd(&counts[src[e]], 1);
}

__global__ void k_scan(const int* __restrict__ counts, int* __restrict__ rowstart,
                       int N, int E) {
    __shared__ int part[1024];
    const int t = threadIdx.x;
    const int CH = (N + 1023) / 1024;
    const int lo = t * CH;
    const int hi = min(lo + CH, N);

    int s = 0;
    for (int i = lo; i < hi; i++) s += counts[i];
    part[t] = s;
    __syncthreads();

    for (int off = 1; off < 1024; off <<= 1) {
        int v = part[t];
        int w = (t >= off) ? part[t - off] : 0;
        __syncthreads();
        part[t] = v + w;
        __syncthreads();
    }

    int run = (t == 0) ? 0 : part[t - 1];
    for (int i = lo; i < hi; i++) {
        rowstart[i] = run;
        run += counts[i];
    }
    if (t == 0) rowstart[N] = E;
}

// place edge payload (rs0,rs1,rs2,u) directly into CSR slot (fast path),
// or just the permutation (fallback when ws too small for eps).
__global__ void k_place(const int* __restrict__ src, const int* __restrict__ rank,
                        const int* __restrict__ rowstart,
                        const void* __restrict__ r_ij, const int* __restrict__ flag,
                        float4* __restrict__ eps, int* __restrict__ perm, int E) {
    int e = blockIdx.x * blockDim.x + threadIdx.x;
    if (e >= E) return;
    const int pos = rowstart[src[e]] + rank[e];
    if (eps) {
        const bool f32 = flag[0] != 0;
        const float x = ldf(r_ij, 3 * e + 0, f32);
        const float y = ldf(r_ij, 3 * e + 1, f32);
        const float z = ldf(r_ij, 3 * e + 2, f32);
        const float d2 = x * x + y * y + z * z;
        const float inv = rsqrtf(1.0f + 49.0f * d2);     // tens_sigmoid(7*r)
        const float u = fminf(sqrtf(d2), DMAX) * ((float)(TSIZE - 1) / DMAX);
        eps[pos] = make_float4(7.0f * x * inv, 7.0f * y * inv, 7.0f * z * inv, u);
    } else {
        perm[pos] = e;
    }
}

// --- per-node accumulation: one wave per node ------------------------------
// lane = (a = lane&31) x (half = lane>>5). half0: {A_a, v*, d0*}; half1: {d1*, d2*}.
__global__ void __launch_bounds__(64 * NPB) k_nodes(
    const float4* __restrict__ eps,          // CSR-ordered payload (fast path)
    const int* __restrict__ perm,            // fallback
    const void* __restrict__ r_ij,
    const int* __restrict__ rowstart,
    const float* __restrict__ tab_a,
    const float* __restrict__ tab_v,
    const float* __restrict__ tab_d,
    const int* __restrict__ flag,
    void* __restrict__ out, int N) {
    const int wave = threadIdx.x >> 6;
    const int lane = threadIdx.x & 63;
    const int n = blockIdx.x * NPB + wave;
    if (n >= N) return;
    const int a = lane & 31;
    const int half = lane >> 5;
    const bool f32 = flag[0] != 0;

    const int s0 = rowstart[n];
    const int s1 = rowstart[n + 1];

    float acc0 = 0.f, acc1 = 0.f, acc2 = 0.f, acc3 = 0.f, acc4 = 0.f, acc5 = 0.f, acc6 = 0.f;

    if (eps) {
        int idx = s0;
        // unrolled x2: both edges' 12 table loads issued together
        for (; idx + 1 < s1; idx += 2) {
            const float4 q0 = eps[idx];
            const float4 q1 = eps[idx + 1];
            const int i0 = min((int)q0.w, TSIZE - 2);
            const int i1 = min((int)q1.w, TSIZE - 2);
            const float f0 = q0.w - (float)i0;
            const float f1 = q1.w - (float)i1;
            const int b0 = i0 * 32 + a;
            const int b1 = i1 * 32 + a;

            const float ra0 = tab_a[b0], ra0b = tab_a[b0 + 32];
            const float rv0 = tab_v[b0], rv0b = tab_v[b0 + 32];
            const float rd0 = tab_d[b0], rd0b = tab_d[b0 + 32];
            const float ra1 = tab_a[b1], ra1b = tab_a[b1 + 32];
            const float rv1 = tab_v[b1], rv1b = tab_v[b1 + 32];
            const float rd1 = tab_d[b1], rd1b = tab_d[b1 + 32];

            const float ra_0 = ra0 + f0 * (ra0b - ra0);
            const float rv_0 = rv0 + f0 * (rv0b - rv0);
            const float rd_0 = rd0 + f0 * (rd0b - rd0);
            const float ra_1 = ra1 + f1 * (ra1b - ra1);
            const float rv_1 = rv1 + f1 * (rv1b - rv1);
            const float rd_1 = rd1 + f1 * (rd1b - rd1);

            if (half == 0) {
                acc0 += ra_0 + ra_1;
                acc1 += rv_0 * q0.x + rv_1 * q1.x;
                acc2 += rv_0 * q0.y + rv_1 * q1.y;
                acc3 += rv_0 * q0.z + rv_1 * q1.z;
                const float t0 = rd_0 * q0.x, t1 = rd_1 * q1.x;
                acc4 += t0 * q0.x + t1 * q1.x;
                acc5 += t0 * q0.y + t1 * q1.y;
                acc6 += t0 * q0.z + t1 * q1.z;
            } else {
                const float p0 = rd_0 * q0.y, p1 = rd_1 * q1.y;
                const float s0v = rd_0 * q0.z, s1v = rd_1 * q1.z;
                acc0 += p0 * q0.x + p1 * q1.x;
                acc1 += p0 * q0.y + p1 * q1.y;
                acc2 += p0 * q0.z + p1 * q1.z;
                acc3 += s0v * q0.x + s1v * q1.x;
                acc4 += s0v * q0.y + s1v * q1.y;
                acc5 += s0v * q0.z + s1v * q1.z;
            }
        }
        if (idx < s1) {   // tail
            const float4 q = eps[idx];
            const int i0 = min((int)q.w, TSIZE - 2);
            const float f = q.w - (float)i0;
            const int b0 = i0 * 32 + a;
            float ra = tab_a[b0], rab = tab_a[b0 + 32];
            float rv = tab_v[b0], rvb = tab_v[b0 + 32];
            float rd = tab_d[b0], rdb = tab_d[b0 + 32];
            ra += f * (rab - ra); rv += f * (rvb - rv); rd += f * (rdb - rd);
            if (half == 0) {
                acc0 += ra;
                acc1 += rv * q.x; acc2 += rv * q.y; acc3 += rv * q.z;
                const float t = rd * q.x;
                acc4 += t * q.x; acc5 += t * q.y; acc6 += t * q.z;
            } else {
                const float p = rd * q.y, s = rd * q.z;
                acc0 += p * q.x; acc1 += p * q.y; acc2 += p * q.z;
                acc3 += s * q.x; acc4 += s * q.y; acc5 += s * q.z;
            }
        }
    } else {
        for (int idx = s0; idx < s1; idx++) {
            const int e = perm[idx];
            const float x = ldf(r_ij, 3 * e + 0, f32);
            const float y = ldf(r_ij, 3 * e + 1, f32);
            const float z = ldf(r_ij, 3 * e + 2, f32);
            const float d2 = x * x + y * y + z * z;
            const float inv = rsqrtf(1.0f + 49.0f * d2);
            const float rs0 = 7.0f * x * inv, rs1 = 7.0f * y * inv, rs2 = 7.0f * z * inv;
            const float u = fminf(sqrtf(d2), DMAX) * ((float)(TSIZE - 1) / DMAX);
            const int i0 = min((int)u, TSIZE - 2);
            const float f = u - (float)i0;
            const int b0 = i0 * 32 + a;
            float ra = tab_a[b0], rab = tab_a[b0 + 32];
            float rv = tab_v[b0], rvb = tab_v[b0 + 32];
            float rd = tab_d[b0], rdb = tab_d[b0 + 32];
            ra += f * (rab - ra); rv += f * (rvb - rv); rd += f * (rdb - rd);
            if (half == 0) {
                acc0 += ra;
                acc1 += rv * rs0; acc2 += rv * rs1; acc3 += rv * rs2;
                const float t = rd * rs0;
                acc4 += t * rs0; acc5 += t * rs1; acc6 += t * rs2;
            } else {
                const float p = rd * rs1, s = rd * rs2;
                acc0 += p * rs0; acc1 += p * rs1; acc2 += p * rs2;
                acc3 += s * rs0; acc4 += s * rs1; acc5 += s * rs2;
            }
        }
    }

    const size_t baseV = (size_t)N * 32;
    const size_t baseD = (size_t)N * 128;
    if (half == 0) {
        stf(out, (size_t)n * 32 + a, acc0, f32);
        const size_t vb = baseV + (size_t)n * 96 + a * 3;
        stf(out, vb + 0, acc1, f32);
        stf(out, vb + 1, acc2, f32);
        stf(out, vb + 2, acc3, f32);
        const size_t db = baseD + (size_t)n * 288 + a * 9;
        stf(out, db + 0, acc4, f32);
        stf(out, db + 1, acc5, f32);
        stf(out, db + 2, acc6, f32);
    } else {
        const size_t db = baseD + (size_t)n * 288 + a * 9;
        stf(out, db + 3, acc0, f32);
        stf(out, db + 4, acc1, f32);
        stf(out, db + 5, acc2, f32);
        stf(out, db + 6, acc3, f32);
        stf(out, db + 7, acc4, f32);
        stf(out, db + 8, acc5, f32);
    }
}

extern "C" void kernel_launch(void* const* d_in, const int* in_sizes, int n_in,
                              void* d_out, int out_size, void* d_ws, size_t ws_size,
                              hipStream_t stream) {
    const void* r_ij     = d_in[0];
    const void* w_rad    = d_in[1];
    const void* b_rad    = d_in[2];
    const void* w_direct = d_in[3];
    const void* w1       = d_in[4];
    const void* b1       = d_in[5];
    const void* w2       = d_in[6];
    const void* b2       = d_in[7];
    const void* w3       = d_in[8];
    const void* b3       = d_in[9];
    const void* w_v      = d_in[10];
    const void* w_d      = d_in[11];
    const int* edges_src = (const int*)d_in[12];

    const int E = in_sizes[12];
    const int N = out_size / 416;   // 32 + 96 + 288 per node

    const size_t epsBytes = (size_t)E * 16;
    const size_t tabBytes = (size_t)3 * TSIZE * 32 * 4;
    const size_t intBytes = (size_t)(4 + N + (N + 1) + E + E) * 4;
    const bool use_eps = ws_size >= epsBytes + tabBytes + intBytes + 64;

    char* w = (char*)d_ws;
    float4* eps  = use_eps ? (float4*)w : nullptr;
    float* tab_a = (float*)(w + (use_eps ? epsBytes : 0));
    float* tab_v = tab_a + TSIZE * 32;
    float* tab_d = tab_v + TSIZE * 32;
    int* flag    = (int*)(tab_d + TSIZE * 32);
    int* counts  = flag + 4;
    int* rowstart = counts + N;           // N+1
    int* rank    = rowstart + N + 1;      // E
    int* perm    = rank + E;              // E (fallback only)

    int nprobe = in_sizes[0] < 8192 ? in_sizes[0] : 8192;
    k_detect<<<1, 256, 0, stream>>>(r_ij, nprobe, flag);
    k_table<<<128, 64, 0, stream>>>(w_rad, b_rad, w_direct, w1, b1, w2, b2,
                                    w3, b3, w_v, w_d, flag, tab_a, tab_v, tab_d);
    k_zero<<<(N + 255) / 256, 256, 0, stream>>>(counts, N);
    k_rank<<<(E + 255) / 256, 256, 0, stream>>>(edges_src, counts, rank, E);
    k_scan<<<1, 1024, 0, stream>>>(counts, rowstart, N, E);
    k_place<<<(E + 255) / 256, 256, 0, stream>>>(edges_src, rank, rowstart,
                                                 r_ij, flag, eps, perm, E);
    k_nodes<<<(N + NPB - 1) / NPB, 64 * NPB, 0, stream>>>(
        eps, perm, r_ij, rowstart, tab_a, tab_v, tab_d, flag, d_out, N);
}